// Round 11
// baseline (289.521 us; speedup 1.0000x reference)
//
#include <hip/hip_runtime.h>
#include <stdint.h>

typedef unsigned short u16;
typedef __bf16 bf16_t;
typedef bf16_t bf16x8 __attribute__((ext_vector_type(8)));
typedef float f32x4 __attribute__((ext_vector_type(4)));
typedef u16 u16x4 __attribute__((ext_vector_type(4)));
typedef u16 u16x8 __attribute__((ext_vector_type(8)));

#define AS1 __attribute__((address_space(1)))
#define AS3 __attribute__((address_space(3)))

__device__ __forceinline__ u16 f2bf(float f) {
  union { float f; uint32_t u; } x; x.f = f;
  uint32_t u = x.u;
  return (u16)((u + 0x7fffu + ((u >> 16) & 1u)) >> 16);  // RNE
}

__device__ __forceinline__ float bf2f(u16 b) {
  union { uint32_t u; float f; } x; x.u = ((uint32_t)b) << 16;
  return x.f;
}

__device__ __forceinline__ void gload_lds16(const void* g, void* lds) {
  __builtin_amdgcn_global_load_lds((const AS1 uint32_t*)g, (AS3 uint32_t*)lds, 16, 0, 0);
}

// ---------------------------------------------------------------------------
// fp32 -> bf16 elementwise convert
// ---------------------------------------------------------------------------
__global__ __launch_bounds__(256) void cvt_bf16(const float* __restrict__ in,
                                                u16* __restrict__ out, int n4) {
  int i = blockIdx.x * 256 + threadIdx.x;
  if (i >= n4) return;
  float4 v = ((const float4*)in)[i];
  u16x4 o = {f2bf(v.x), f2bf(v.y), f2bf(v.z), f2bf(v.w)};
  *(u16x4*)(out + (size_t)i * 4) = o;
}

// ---------------------------------------------------------------------------
// r9/r10 NaN post-mortem (both failed IDENTICALLY, so compiler-order pins
// were not the issue): the counted fence vmcnt(8) assumed vmcnt retires in
// issue order ACROSS MIXED op types. global_load_lds (LDS-return path) and
// global_load (VGPR-return path) are different datapaths; retirement order
// across types is NOT guaranteed -- a B load retiring early satisfies
// vmcnt(8) while a stageA op is still in flight -> ldsA reads incomplete
// LDS -> NaN. Lesson: counted vmcnt windows must contain a UNIFORM op type
// (m201/AITER templates do). r11 fix: keep B-in-registers (the real win:
// gemm128 LDS/tile 176->80KB) but fence with vmcnt(0) -- correct under any
// retirement order. B(t+1) regs still issued a full tile early; at the
// fence they've been in flight ~1 MFMA burst, L2 latency mostly covered.
// ---------------------------------------------------------------------------
#define BARRIER() do { asm volatile("" ::: "memory"); \
                       __builtin_amdgcn_s_barrier();  \
                       asm volatile("" ::: "memory"); } while (0)

#define MQS(MQi, NQi, ASET, BSET)                                              \
  do {                                                                         \
    __builtin_amdgcn_s_setprio(1);                                             \
    _Pragma("unroll") for (int j_ = 0; j_ < 4; ++j_) {                         \
      _Pragma("unroll") for (int i_ = 0; i_ < 2; ++i_) {                       \
        acc[(MQi) * 4 + j_][(NQi) * 2 + i_] =                                  \
            __builtin_amdgcn_mfma_f32_16x16x32_bf16(                           \
                ASET[j_][0], BSET[i_][0],                                      \
                acc[(MQi) * 4 + j_][(NQi) * 2 + i_], 0, 0, 0);                 \
        acc[(MQi) * 4 + j_][(NQi) * 2 + i_] =                                  \
            __builtin_amdgcn_mfma_f32_16x16x32_bf16(                           \
                ASET[j_][1], BSET[i_][1],                                      \
                acc[(MQi) * 4 + j_][(NQi) * 2 + i_], 0, 0, 0);                 \
      }                                                                        \
    }                                                                          \
    __builtin_amdgcn_s_setprio(0);                                             \
  } while (0)

// ---------------------------------------------------------------------------
// gemm256: 256x256 tile, 8 waves 2Mx4N, reg-dbuf (round-3 winner, FROZEN).
// A: [M][K] lda, B: [N][K] ldb, C: [M][N] ldc, z via sAz/sBz/sCz.
// M=gridDim.y*256, N=gridDim.x*256, K%64==0, nt>=2.
// ---------------------------------------------------------------------------
template <bool BF16OUT>
__global__ __launch_bounds__(512, 2)
void gemm256(const u16* __restrict__ A, const u16* __restrict__ B,
             void* __restrict__ Cv,
             int lda, int ldb, int ldc,
             long long sAz, long long sBz, long long sCz,
             int K, float alpha) {
  __shared__ u16 As[2][256 * 64];   // 64 KiB
  __shared__ u16 Bs[2][256 * 64];   // 64 KiB
  const int tid  = threadIdx.x;
  const int lane = tid & 63;
  const int wid  = tid >> 6;        // 0..7
  const int wr   = wid >> 2;        // 0..1
  const int wc   = wid & 3;         // 0..3
  const long long z = blockIdx.z;
  const u16* Ab = A + z * sAz;
  const u16* Bb = B + z * sBz;
  const int rowBase = blockIdx.y * 256;
  const int colBase = blockIdx.x * 256;
  const int nt = K >> 6;

  const int sRow   = tid >> 3;                    // 0..63
  const int sChunk = (tid & 7) ^ (sRow & 7);      // rule-21 involution
  const size_t ldaS = (size_t)lda, ldbS = (size_t)ldb;
  const u16* aS = Ab + (size_t)(rowBase + sRow) * ldaS + sChunk * 8;
  const u16* bS = Bb + (size_t)(colBase + sRow) * ldbS + sChunk * 8;

  const int fr = lane & 15;
  const int kx = lane >> 4;
  const int rx = lane & 7;

  f32x4 acc[8][4];
  const f32x4 zf = {0.f, 0.f, 0.f, 0.f};
#pragma unroll
  for (int m = 0; m < 8; ++m)
#pragma unroll
    for (int n = 0; n < 4; ++n) acc[m][n] = zf;

  bf16x8 Ara[4][2], Arb[4][2], Bra[2][2], Brb[2][2];

  auto stageA = [&](int buf, int h, int kt) {
    const u16* s = aS + (size_t)(h * 128) * ldaS + kt;
    char* d = ((char*)&As[buf][0]) + h * 16384 + tid * 16;
    gload_lds16(s, d);
    gload_lds16(s + 64 * ldaS, d + 8192);
  };
  auto stageB = [&](int buf, int h, int kt) {
    const u16* s = bS + (size_t)(h * 128) * ldbS + kt;
    char* d = ((char*)&Bs[buf][0]) + h * 16384 + tid * 16;
    gload_lds16(s, d);
    gload_lds16(s + 64 * ldbS, d + 8192);
  };
  auto ldsA = [&](int buf, int mq, bf16x8 (&dst)[4][2]) {
#pragma unroll
    for (int j = 0; j < 4; ++j) {
      const int row = mq * 128 + wr * 64 + j * 16 + fr;
#pragma unroll
      for (int k = 0; k < 2; ++k) {
        const int ch = ((k * 4 + kx) ^ rx) * 8;
        dst[j][k] = *(const bf16x8*)&As[buf][row * 64 + ch];
      }
    }
  };
  auto ldsB = [&](int buf, int nq, bf16x8 (&dst)[2][2]) {
#pragma unroll
    for (int i = 0; i < 2; ++i) {
      const int row = nq * 128 + i * 64 + wc * 16 + fr;
#pragma unroll
      for (int k = 0; k < 2; ++k) {
        const int ch = ((k * 4 + kx) ^ rx) * 8;
        dst[i][k] = *(const bf16x8*)&Bs[buf][row * 64 + ch];
      }
    }
  };

  stageA(0, 0, 0);
  stageA(0, 1, 0);
  stageB(0, 0, 0);
  stageB(0, 1, 0);
  asm volatile("s_waitcnt vmcnt(0)" ::: "memory");
  BARRIER();
  ldsA(0, 0, Ara);              // A0(0)
  ldsB(0, 0, Bra);              // B0(0)

  for (int t = 0; t < nt; ++t) {
    const int c = t & 1;
    const int kt1 = (t + 1) << 6;
    const bool s1 = (t + 1 < nt);
    ldsB(c, 1, Brb);            // B1(t)
    ldsA(c, 1, Arb);            // A1(t)
    if (s1) {
      stageA(1 - c, 0, kt1);
      stageA(1 - c, 1, kt1);
      stageB(1 - c, 0, kt1);
      stageB(1 - c, 1, kt1);
    }
    MQS(0, 0, Ara, Bra);
    MQS(0, 1, Ara, Brb);
    if (s1) {
      asm volatile("s_waitcnt lgkmcnt(0)" ::: "memory");
      asm volatile("s_waitcnt vmcnt(0)" ::: "memory");
      BARRIER();
      ldsA(1 - c, 0, Ara);      // A0(t+1)
      __builtin_amdgcn_sched_barrier(0);
    }
    MQS(1, 0, Arb, Bra);
    if (s1) ldsB(1 - c, 0, Bra);// B0(t+1)
    MQS(1, 1, Arb, Brb);
  }

  const int r0 = (lane >> 4) * 4;
#pragma unroll
  for (int m = 0; m < 8; ++m) {
    const int grow = rowBase + (m >> 2) * 128 + wr * 64 + (m & 3) * 16 + r0;
#pragma unroll
    for (int jj = 0; jj < 4; ++jj) {
      const size_t rOff = (size_t)(grow + jj) * (size_t)ldc;
      if constexpr (BF16OUT) {
        u16* C = (u16*)Cv + z * sCz;
#pragma unroll
        for (int n = 0; n < 4; ++n) {
          const int gcol = colBase + (n >> 1) * 128 + (n & 1) * 64 + wc * 16 + fr;
          C[rOff + gcol] = f2bf(acc[m][n][jj] * alpha);
        }
      } else {
        float* C = (float*)Cv + z * sCz;
#pragma unroll
        for (int n = 0; n < 4; ++n) {
          const int gcol = colBase + (n >> 1) * 128 + (n & 1) * 64 + wc * 16 + fr;
          C[rOff + gcol] = acc[m][n][jj] * alpha;
        }
      }
    }
  }
}

// ---------------------------------------------------------------------------
// gemm128: 128x256 tile, B-IN-REGISTERS (r11 = r10 with vmcnt(0) fences --
// no cross-type retirement-order assumption). 8 waves 2Mx4N, wave owns
// 64x64, acc[4][4]. A LDS-staged (reg-dbuf, unroll-of-2); B(t+1) fragments
// global->VGPR at tile-t start (full-tile prefetch distance; drained at the
// mid-tile fence, one MFMA burst after issue -- L2 latency mostly covered).
// LDS = As only, 32 KiB; LDS traffic/tile 176->80KB vs r8.
// nt = K/64 EVEN, >= 2. M=gridDim.y*128, N=gridDim.x*256.
// ---------------------------------------------------------------------------
template <bool BF16OUT>
__global__ __launch_bounds__(512, 2)
void gemm128(const u16* __restrict__ A, const u16* __restrict__ B,
             void* __restrict__ Cv,
             int lda, int ldb, int ldc,
             long long sAz, long long sBz, long long sCz,
             int K, float alpha) {
  __shared__ u16 As[2][128 * 64];   // 32 KiB total
  const int tid  = threadIdx.x;
  const int lane = tid & 63;
  const int wid  = tid >> 6;        // 0..7
  const int wr   = wid >> 2;        // 0..1
  const int wc   = wid & 3;         // 0..3
  const long long z = blockIdx.z;
  const u16* Ab = A + z * sAz;
  const u16* Bb = B + z * sBz;
  const int rowBase = blockIdx.y * 128;
  const int colBase = blockIdx.x * 256;
  const int nt = K >> 6;            // must be even, >= 2

  const int sRow   = tid >> 3;                    // 0..63
  const int sChunk = (tid & 7) ^ (sRow & 7);
  const size_t ldaS = (size_t)lda, ldbS = (size_t)ldb;
  const u16* aS = Ab + (size_t)(rowBase + sRow) * ldaS + sChunk * 8;

  const int fr = lane & 15;
  const int kx = lane >> 4;
  const int rx = lane & 7;

  f32x4 acc[4][4];
  const f32x4 zf = {0.f, 0.f, 0.f, 0.f};
#pragma unroll
  for (int m = 0; m < 4; ++m)
#pragma unroll
    for (int n = 0; n < 4; ++n) acc[m][n] = zf;

  // A: 2 reg sets (dbuf); B: 2 double-sets (cur/next), all statically indexed
  bf16x8 Ara[4][2], Arb[4][2];
  bf16x8 B0a[2][2], B1a[2][2], B0b[2][2], B1b[2][2];

  auto stageA = [&](int buf, int kt) {
    const u16* s = aS + kt;
    char* d = ((char*)&As[buf][0]) + tid * 16;
    gload_lds16(s, d);
    gload_lds16(s + 64 * ldaS, d + 8192);
  };
  auto ldsA = [&](int buf, bf16x8 (&dst)[4][2]) {
#pragma unroll
    for (int j = 0; j < 4; ++j) {
      const int row = wr * 64 + j * 16 + fr;            // < 128
#pragma unroll
      for (int k = 0; k < 2; ++k) {
        const int ch = ((k * 4 + kx) ^ rx) * 8;
        dst[j][k] = *(const bf16x8*)&As[buf][row * 64 + ch];
      }
    }
  };
  // B fragments straight from global into regs (unswizzled per-lane addr;
  // per 16-lane group the (kx,k) chunks tile each 128B row exactly).
  auto gloadB = [&](bf16x8 (&dst)[2][2], int nq, int kt) {
#pragma unroll
    for (int i = 0; i < 2; ++i) {
      const u16* src =
          Bb + (size_t)(colBase + nq * 128 + i * 64 + wc * 16 + fr) * ldbS + kt;
#pragma unroll
      for (int k = 0; k < 2; ++k) {
        dst[i][k] = *(const bf16x8*)(src + (k * 4 + kx) * 8);
      }
    }
  };

  // one tile: ACUR/BC* hold tile t operands; ANXT/BN* receive tile t+1.
  auto tile = [&](int t, int c, bf16x8 (&ACUR)[4][2], bf16x8 (&ANXT)[4][2],
                  bf16x8 (&BC0)[2][2], bf16x8 (&BC1)[2][2],
                  bf16x8 (&BN0)[2][2], bf16x8 (&BN1)[2][2]) {
    const int kt1 = (t + 1) << 6;
    const bool s1 = (t + 1 < nt);
    if (s1) {
      stageA(1 - c, kt1);       // 2 gload_lds, issued first
      __builtin_amdgcn_sched_barrier(0);
      gloadB(BN0, 0, kt1);      // 8 reg loads; consumed next tile
      gloadB(BN1, 1, kt1);
      __builtin_amdgcn_sched_barrier(0);  // pin: issue block before MFMA
    }
    MQS(0, 0, ACUR, BC0);       // acc cols 0,1
    if (s1) {
      asm volatile("s_waitcnt lgkmcnt(0)" ::: "memory");
      asm volatile("s_waitcnt vmcnt(0)" ::: "memory");   // ALL vmem drained
      BARRIER();
      ldsA(1 - c, ANXT);        // A(t+1), 8 reads; drains under MQS(0,1)
      __builtin_amdgcn_sched_barrier(0);
    }
    MQS(0, 1, ACUR, BC1);       // acc cols 2,3
  };

  // prologue: A(0)->As[0], B(0)->regs; vmcnt(0) drains everything.
  stageA(0, 0);
  __builtin_amdgcn_sched_barrier(0);
  gloadB(B0a, 0, 0);
  gloadB(B1a, 1, 0);
  asm volatile("s_waitcnt vmcnt(0)" ::: "memory");
  __builtin_amdgcn_sched_barrier(0);
  BARRIER();
  ldsA(0, Ara);                 // A(0)

  for (int tt = 0; tt < nt; tt += 2) {
    tile(tt,     0, Ara, Arb, B0a, B1a, B0b, B1b);
    tile(tt + 1, 1, Arb, Ara, B0b, B1b, B0a, B1a);
  }

  // epilogue: C/D layout col=lane&15, row=(lane>>4)*4+reg [m89-verified]
  const int r0 = (lane >> 4) * 4;
#pragma unroll
  for (int m = 0; m < 4; ++m) {
    const int grow = rowBase + wr * 64 + m * 16 + r0;
#pragma unroll
    for (int jj = 0; jj < 4; ++jj) {
      const size_t rOff = (size_t)(grow + jj) * (size_t)ldc;
      if constexpr (BF16OUT) {
        u16* C = (u16*)Cv + z * sCz;
#pragma unroll
        for (int n = 0; n < 4; ++n) {
          const int gcol = colBase + (n >> 1) * 128 + (n & 1) * 64 + wc * 16 + fr;
          C[rOff + gcol] = f2bf(acc[m][n][jj] * alpha);
        }
      } else {
        float* C = (float*)Cv + z * sCz;
#pragma unroll
        for (int n = 0; n < 4; ++n) {
          const int gcol = colBase + (n >> 1) * 128 + (n & 1) * 64 + wc * 16 + fr;
          C[rOff + gcol] = acc[m][n][jj] * alpha;
        }
      }
    }
  }
}

// ---------------------------------------------------------------------------
// Row softmax over 2048 cols: reads bf16 scores (already scaled by 1/32),
// writes fp32 weights (required output) + bf16 probs IN PLACE over scores.
// ---------------------------------------------------------------------------
__global__ __launch_bounds__(256)
void softmax_rows(u16* __restrict__ sbf, float* __restrict__ wfp) {
  const size_t row = blockIdx.x;
  const int tid = threadIdx.x;
  u16* pb = sbf + row * 2048;
  u16x8 xb = *(const u16x8*)(pb + tid * 8);
  float x[8];
#pragma unroll
  for (int j = 0; j < 8; ++j) x[j] = bf2f(xb[j]);
  float m = x[0];
#pragma unroll
  for (int j = 1; j < 8; ++j) m = fmaxf(m, x[j]);
#pragma unroll
  for (int o = 32; o; o >>= 1) m = fmaxf(m, __shfl_xor(m, o, 64));
  __shared__ float red[8];
  if ((tid & 63) == 0) red[tid >> 6] = m;
  __syncthreads();
  m = fmaxf(fmaxf(red[0], red[1]), fmaxf(red[2], red[3]));
  float e[8];
  float s = 0.f;
#pragma unroll
  for (int j = 0; j < 8; ++j) { e[j] = expf(x[j] - m); s += e[j]; }
#pragma unroll
  for (int o = 32; o; o >>= 1) s += __shfl_xor(s, o, 64);
  if ((tid & 63) == 0) red[4 + (tid >> 6)] = s;
  __syncthreads();
  s = (red[4] + red[5]) + (red[6] + red[7]);
  const float inv = 1.0f / s;
  float w[8];
#pragma unroll
  for (int j = 0; j < 8; ++j) w[j] = e[j] * inv;
  float* pf = wfp + row * 2048;
  float4 o0 = {w[0], w[1], w[2], w[3]};
  float4 o1 = {w[4], w[5], w[6], w[7]};
  ((float4*)pf)[tid * 2] = o0;
  ((float4*)pf)[tid * 2 + 1] = o1;
  u16x8 ub;
#pragma unroll
  for (int j = 0; j < 8; ++j) ub[j] = f2bf(w[j]);
  *(u16x8*)(pb + tid * 8) = ub;
}

// ---------------------------------------------------------------------------
// S=2048, B=4, E=1024. inputs: Q, K(ignored), V(ignored), W_in, W_out (fp32)
// outputs: out [2048,4,1024] fp32 | weights [4,2048,2048] fp32
// Graph: cvt -> qkv(p1 q,k | p2 v) -> {scores -> softmax | VWT} -> out'
// with out = P * (V * Wo^T)   [associativity; same FLOPs, no transpose_v]
// ---------------------------------------------------------------------------
extern "C" void kernel_launch(void* const* d_in, const int* in_sizes, int n_in,
                              void* d_out, int out_size, void* d_ws, size_t ws_size,
                              hipStream_t stream) {
  const float* Q  = (const float*)d_in[0];
  const float* Wi = (const float*)d_in[3];
  const float* Wo = (const float*)d_in[4];
  float* out0    = (float*)d_out;
  float* weights = out0 + (size_t)2048 * 4 * 1024;  // 8388608

  char* ws = (char*)d_ws;
  u16* Qb   = (u16*)(ws);                          // 16 MiB [8192][1024]
  u16* Wib  = (u16*)(ws + ((size_t)16 << 20));     //  6 MiB [3072][1024]
  u16* Wob  = (u16*)(ws + ((size_t)22 << 20));     //  2 MiB [1024][1024]
  u16* qkvb = (u16*)(ws + ((size_t)24 << 20));     // 48 MiB [8192][3072]
  u16* vwT  = (u16*)(ws + ((size_t)72 << 20));     // 16 MiB [4][1024f][2048s]
  u16* wbf  = (u16*)(ws + ((size_t)88 << 20));     // 32 MiB [4][2048][2048]

  // 1) converts
  cvt_bf16<<<dim3(8192), dim3(256), 0, stream>>>(Q,  Qb,  2097152);
  cvt_bf16<<<dim3(3072), dim3(256), 0, stream>>>(Wi, Wib, 786432);
  cvt_bf16<<<dim3(1024), dim3(256), 0, stream>>>(Wo, Wob, 262144);

  // 2a) qkv cols 0..2047 (q,k): 8x32 = 256 blocks, exactly 1 round
  gemm256<true><<<dim3(8, 32, 1), dim3(512), 0, stream>>>(
      Qb, Wib, (void*)qkvb, 1024, 1024, 3072, 0, 0, 0, 1024, 1.0f);

  // 2b) qkv cols 2048..3071 (v): 128-row tiles, 4x64 = 256 blocks
  gemm128<true><<<dim3(4, 64, 1), dim3(512), 0, stream>>>(
      Qb, Wib + (size_t)2048 * 1024, (void*)(qkvb + 2048),
      1024, 1024, 3072, 0, 0, 0, 1024, 1.0f);

  // 3) scores[b] = (q/32) k^T -> bf16 into wbf (8x8x4 = 256 blocks)
  gemm256<true><<<dim3(8, 8, 4), dim3(512), 0, stream>>>(
      qkvb, qkvb + 1024, (void*)wbf, 12288, 12288, 2048,
      3072LL, 3072LL, 4194304LL, 1024, 0.03125f);

  // 4) VWT[b][f][s] = sum_e Wo[f,e] v[b,s,e]  (A=Wob shared, B=v rows)
  //    8x8x4 = 256 blocks, nt=16
  gemm128<true><<<dim3(8, 8, 4), dim3(512), 0, stream>>>(
      Wob, qkvb + 2048, (void*)vwT, 1024, 12288, 2048,
      0LL, 3072LL, 2097152LL, 1024, 1.0f);

  // 5) softmax: bf16 scores -> fp32 weights (d_out) + bf16 probs in place
  softmax_rows<<<dim3(8192), dim3(256), 0, stream>>>(wbf, weights);

  // 6) out[t,b,f] = sum_s P[b,t,s] VWT[b,f,s] -> fp32 d_out directly
  //    4x16x4 = 256 blocks, nt=32
  gemm128<false><<<dim3(4, 16, 4), dim3(512), 0, stream>>>(
      wbf, vwT, (void*)out0, 2048, 2048, 4096,
      4194304LL, 2097152LL, 1024LL, 2048, 1.0f);
}

// Round 12
// 197.376 us; speedup vs baseline: 1.4669x; 1.4669x over previous
//
#include <hip/hip_runtime.h>
#include <stdint.h>

typedef unsigned short u16;
typedef __bf16 bf16_t;
typedef bf16_t bf16x8 __attribute__((ext_vector_type(8)));
typedef float f32x4 __attribute__((ext_vector_type(4)));
typedef u16 u16x4 __attribute__((ext_vector_type(4)));
typedef u16 u16x8 __attribute__((ext_vector_type(8)));

#define AS1 __attribute__((address_space(1)))
#define AS3 __attribute__((address_space(3)))

__device__ __forceinline__ u16 f2bf(float f) {
  union { float f; uint32_t u; } x; x.f = f;
  uint32_t u = x.u;
  return (u16)((u + 0x7fffu + ((u >> 16) & 1u)) >> 16);  // RNE
}

__device__ __forceinline__ float bf2f(u16 b) {
  union { uint32_t u; float f; } x; x.u = ((uint32_t)b) << 16;
  return x.f;
}

__device__ __forceinline__ void gload_lds16(const void* g, void* lds) {
  __builtin_amdgcn_global_load_lds((const AS1 uint32_t*)g, (AS3 uint32_t*)lds, 16, 0, 0);
}

// XCD-chunked bijective block remap (T1). HW round-robins linear block id
// across 8 XCDs (lin%8 = XCD); remapping work = (lin%8)*q + lin/8 gives each
// XCD a CONTIGUOUS work chunk so blocks sharing an A row-panel hit the same
// per-XCD L2 -> the loads drained at the mid-tile fence complete at L2
// latency (~200cyc) not HBM (~900cyc). Requires total blocks % 8 == 0
// (all our grids are 256). Correctness-neutral (bijection).
__device__ __forceinline__ void xcd_remap(int& bx, int& by, int& bz) {
  const int gx = gridDim.x, gy = gridDim.y;
  const int n = gx * gy * gridDim.z;
  const int lin = blockIdx.x + gx * (blockIdx.y + gy * blockIdx.z);
  const int q = n >> 3;
  const int work = (lin & 7) * q + (lin >> 3);
  bx = work % gx;
  const int t = work / gx;
  by = t % gy;
  bz = t / gy;
}

// ---------------------------------------------------------------------------
// fp32 -> bf16 elementwise convert
// ---------------------------------------------------------------------------
__global__ __launch_bounds__(256) void cvt_bf16(const float* __restrict__ in,
                                                u16* __restrict__ out, int n4) {
  int i = blockIdx.x * 256 + threadIdx.x;
  if (i >= n4) return;
  float4 v = ((const float4*)in)[i];
  u16x4 o = {f2bf(v.x), f2bf(v.y), f2bf(v.z), f2bf(v.w)};
  *(u16x4*)(out + (size_t)i * 4) = o;
}

// ---------------------------------------------------------------------------
// Session record: r8 = 211.6us (best). r9-r11 B-in-registers arc FAILED
// (r6 -37us uncovered latency; r9/r10 NaN -- counted vmcnt across MIXED op
// types [global_load_lds vs global_load] is unsafe, retirement order not
// guaranteed; r11 vmcnt(0)-safe variant = forced full drain of fresh loads,
// gemm128 30->89us). VERDICT: B stays LDS-staged. r12 = r8 revert + T1
// XCD-chunked block swizzle on both GEMMs (latency-bound drain -> L2-local
// A panels shorten the drained loads; FETCH_SIZE 80.5MB showed 4-5x A
// re-fetch across XCDs).
// ---------------------------------------------------------------------------
#define BARRIER() do { asm volatile("" ::: "memory"); \
                       __builtin_amdgcn_s_barrier();  \
                       asm volatile("" ::: "memory"); } while (0)

#define MQS(MQi, NQi, ASET, BSET)                                              \
  do {                                                                         \
    __builtin_amdgcn_s_setprio(1);                                             \
    _Pragma("unroll") for (int j_ = 0; j_ < 4; ++j_) {                         \
      _Pragma("unroll") for (int i_ = 0; i_ < 2; ++i_) {                       \
        acc[(MQi) * 4 + j_][(NQi) * 2 + i_] =                                  \
            __builtin_amdgcn_mfma_f32_16x16x32_bf16(                           \
                ASET[j_][0], BSET[i_][0],                                      \
                acc[(MQi) * 4 + j_][(NQi) * 2 + i_], 0, 0, 0);                 \
        acc[(MQi) * 4 + j_][(NQi) * 2 + i_] =                                  \
            __builtin_amdgcn_mfma_f32_16x16x32_bf16(                           \
                ASET[j_][1], BSET[i_][1],                                      \
                acc[(MQi) * 4 + j_][(NQi) * 2 + i_], 0, 0, 0);                 \
      }                                                                        \
    }                                                                          \
    __builtin_amdgcn_s_setprio(0);                                             \
  } while (0)

// ---------------------------------------------------------------------------
// gemm256: 256x256 tile, 8 waves 2Mx4N, reg-dbuf (round-3 winner, FROZEN
// except T1 remap). A: [M][K] lda, B: [N][K] ldb, C: [M][N] ldc, z via
// sAz/sBz/sCz. M=gridDim.y*256, N=gridDim.x*256, K%64==0, nt>=2,
// total blocks % 8 == 0.
// ---------------------------------------------------------------------------
template <bool BF16OUT>
__global__ __launch_bounds__(512, 2)
void gemm256(const u16* __restrict__ A, const u16* __restrict__ B,
             void* __restrict__ Cv,
             int lda, int ldb, int ldc,
             long long sAz, long long sBz, long long sCz,
             int K, float alpha) {
  __shared__ u16 As[2][256 * 64];   // 64 KiB
  __shared__ u16 Bs[2][256 * 64];   // 64 KiB
  int bx, by, bz;
  xcd_remap(bx, by, bz);
  const int tid  = threadIdx.x;
  const int lane = tid & 63;
  const int wid  = tid >> 6;        // 0..7
  const int wr   = wid >> 2;        // 0..1
  const int wc   = wid & 3;         // 0..3
  const long long z = bz;
  const u16* Ab = A + z * sAz;
  const u16* Bb = B + z * sBz;
  const int rowBase = by * 256;
  const int colBase = bx * 256;
  const int nt = K >> 6;

  const int sRow   = tid >> 3;                    // 0..63
  const int sChunk = (tid & 7) ^ (sRow & 7);      // rule-21 involution
  const size_t ldaS = (size_t)lda, ldbS = (size_t)ldb;
  const u16* aS = Ab + (size_t)(rowBase + sRow) * ldaS + sChunk * 8;
  const u16* bS = Bb + (size_t)(colBase + sRow) * ldbS + sChunk * 8;

  const int fr = lane & 15;
  const int kx = lane >> 4;
  const int rx = lane & 7;

  f32x4 acc[8][4];
  const f32x4 zf = {0.f, 0.f, 0.f, 0.f};
#pragma unroll
  for (int m = 0; m < 8; ++m)
#pragma unroll
    for (int n = 0; n < 4; ++n) acc[m][n] = zf;

  bf16x8 Ara[4][2], Arb[4][2], Bra[2][2], Brb[2][2];

  auto stageA = [&](int buf, int h, int kt) {
    const u16* s = aS + (size_t)(h * 128) * ldaS + kt;
    char* d = ((char*)&As[buf][0]) + h * 16384 + tid * 16;
    gload_lds16(s, d);
    gload_lds16(s + 64 * ldaS, d + 8192);
  };
  auto stageB = [&](int buf, int h, int kt) {
    const u16* s = bS + (size_t)(h * 128) * ldbS + kt;
    char* d = ((char*)&Bs[buf][0]) + h * 16384 + tid * 16;
    gload_lds16(s, d);
    gload_lds16(s + 64 * ldbS, d + 8192);
  };
  auto ldsA = [&](int buf, int mq, bf16x8 (&dst)[4][2]) {
#pragma unroll
    for (int j = 0; j < 4; ++j) {
      const int row = mq * 128 + wr * 64 + j * 16 + fr;
#pragma unroll
      for (int k = 0; k < 2; ++k) {
        const int ch = ((k * 4 + kx) ^ rx) * 8;
        dst[j][k] = *(const bf16x8*)&As[buf][row * 64 + ch];
      }
    }
  };
  auto ldsB = [&](int buf, int nq, bf16x8 (&dst)[2][2]) {
#pragma unroll
    for (int i = 0; i < 2; ++i) {
      const int row = nq * 128 + i * 64 + wc * 16 + fr;
#pragma unroll
      for (int k = 0; k < 2; ++k) {
        const int ch = ((k * 4 + kx) ^ rx) * 8;
        dst[i][k] = *(const bf16x8*)&Bs[buf][row * 64 + ch];
      }
    }
  };

  stageA(0, 0, 0);
  stageA(0, 1, 0);
  stageB(0, 0, 0);
  stageB(0, 1, 0);
  asm volatile("s_waitcnt vmcnt(0)" ::: "memory");
  BARRIER();
  ldsA(0, 0, Ara);              // A0(0)
  ldsB(0, 0, Bra);              // B0(0)

  for (int t = 0; t < nt; ++t) {
    const int c = t & 1;
    const int kt1 = (t + 1) << 6;
    const bool s1 = (t + 1 < nt);
    ldsB(c, 1, Brb);            // B1(t)
    ldsA(c, 1, Arb);            // A1(t)
    if (s1) {
      stageA(1 - c, 0, kt1);
      stageA(1 - c, 1, kt1);
      stageB(1 - c, 0, kt1);
      stageB(1 - c, 1, kt1);
    }
    MQS(0, 0, Ara, Bra);
    MQS(0, 1, Ara, Brb);
    if (s1) {
      asm volatile("s_waitcnt lgkmcnt(0)" ::: "memory");
      asm volatile("s_waitcnt vmcnt(0)" ::: "memory");
      BARRIER();
      ldsA(1 - c, 0, Ara);      // A0(t+1)
      __builtin_amdgcn_sched_barrier(0);
    }
    MQS(1, 0, Arb, Bra);
    if (s1) ldsB(1 - c, 0, Bra);// B0(t+1)
    MQS(1, 1, Arb, Brb);
  }

  const int r0 = (lane >> 4) * 4;
#pragma unroll
  for (int m = 0; m < 8; ++m) {
    const int grow = rowBase + (m >> 2) * 128 + wr * 64 + (m & 3) * 16 + r0;
#pragma unroll
    for (int jj = 0; jj < 4; ++jj) {
      const size_t rOff = (size_t)(grow + jj) * (size_t)ldc;
      if constexpr (BF16OUT) {
        u16* C = (u16*)Cv + z * sCz;
#pragma unroll
        for (int n = 0; n < 4; ++n) {
          const int gcol = colBase + (n >> 1) * 128 + (n & 1) * 64 + wc * 16 + fr;
          C[rOff + gcol] = f2bf(acc[m][n][jj] * alpha);
        }
      } else {
        float* C = (float*)Cv + z * sCz;
#pragma unroll
        for (int n = 0; n < 4; ++n) {
          const int gcol = colBase + (n >> 1) * 128 + (n & 1) * 64 + wc * 16 + fr;
          C[rOff + gcol] = acc[m][n][jj] * alpha;
        }
      }
    }
  }
}

// ---------------------------------------------------------------------------
// gemm128: 128x256 tile, LDS-staged (r7/r8 proven version + T1 remap).
// 8 waves 2Mx4N, wave owns 64x64, acc[4][4]. A reg sets alternate per tile
// via unroll-of-2; LDS 96KiB. nt = K/64 EVEN, >= 2. M=gridDim.y*128,
// N=gridDim.x*256, total blocks % 8 == 0.
// ---------------------------------------------------------------------------
template <bool BF16OUT>
__global__ __launch_bounds__(512, 2)
void gemm128(const u16* __restrict__ A, const u16* __restrict__ B,
             void* __restrict__ Cv,
             int lda, int ldb, int ldc,
             long long sAz, long long sBz, long long sCz,
             int K, float alpha) {
  __shared__ u16 As[2][128 * 64];   // 32 KiB
  __shared__ u16 Bs[2][256 * 64];   // 64 KiB
  int bx, by, bz;
  xcd_remap(bx, by, bz);
  const int tid  = threadIdx.x;
  const int lane = tid & 63;
  const int wid  = tid >> 6;        // 0..7
  const int wr   = wid >> 2;        // 0..1
  const int wc   = wid & 3;         // 0..3
  const long long z = bz;
  const u16* Ab = A + z * sAz;
  const u16* Bb = B + z * sBz;
  const int rowBase = by * 128;
  const int colBase = bx * 256;
  const int nt = K >> 6;            // must be even, >= 2

  const int sRow   = tid >> 3;                    // 0..63
  const int sChunk = (tid & 7) ^ (sRow & 7);
  const size_t ldaS = (size_t)lda, ldbS = (size_t)ldb;
  const u16* aS = Ab + (size_t)(rowBase + sRow) * ldaS + sChunk * 8;
  const u16* bS = Bb + (size_t)(colBase + sRow) * ldbS + sChunk * 8;

  const int fr = lane & 15;
  const int kx = lane >> 4;
  const int rx = lane & 7;

  f32x4 acc[4][4];
  const f32x4 zf = {0.f, 0.f, 0.f, 0.f};
#pragma unroll
  for (int m = 0; m < 4; ++m)
#pragma unroll
    for (int n = 0; n < 4; ++n) acc[m][n] = zf;

  bf16x8 Ara[4][2], Arb[4][2], Bra[2][2], Brb[2][2];

  auto stageA = [&](int buf, int kt) {
    const u16* s = aS + kt;
    char* d = ((char*)&As[buf][0]) + tid * 16;
    gload_lds16(s, d);
    gload_lds16(s + 64 * ldaS, d + 8192);
  };
  auto stageB = [&](int buf, int h, int kt) {
    const u16* s = bS + (size_t)(h * 128) * ldbS + kt;
    char* d = ((char*)&Bs[buf][0]) + h * 16384 + tid * 16;
    gload_lds16(s, d);
    gload_lds16(s + 64 * ldbS, d + 8192);
  };
  auto ldsA = [&](int buf, bf16x8 (&dst)[4][2]) {
#pragma unroll
    for (int j = 0; j < 4; ++j) {
      const int row = wr * 64 + j * 16 + fr;            // < 128
#pragma unroll
      for (int k = 0; k < 2; ++k) {
        const int ch = ((k * 4 + kx) ^ rx) * 8;
        dst[j][k] = *(const bf16x8*)&As[buf][row * 64 + ch];
      }
    }
  };
  auto ldsB = [&](int buf, int nq, bf16x8 (&dst)[2][2]) {
#pragma unroll
    for (int i = 0; i < 2; ++i) {
      const int row = nq * 128 + i * 64 + wc * 16 + fr;
#pragma unroll
      for (int k = 0; k < 2; ++k) {
        const int ch = ((k * 4 + kx) ^ rx) * 8;
        dst[i][k] = *(const bf16x8*)&Bs[buf][row * 64 + ch];
      }
    }
  };

  auto tile = [&](int t, int c, bf16x8 (&ACUR)[4][2], bf16x8 (&ANXT)[4][2]) {
    const int kt1 = (t + 1) << 6;
    const bool s1 = (t + 1 < nt);
    ldsB(c, 1, Brb);            // Bq1(t)
    if (s1) {
      stageA(1 - c, kt1);
      stageB(1 - c, 0, kt1);
      stageB(1 - c, 1, kt1);
    }
    MQS(0, 0, ACUR, Bra);       // acc cols 0,1; last use of Bra=Bq0(t)
    if (s1) {
      asm volatile("s_waitcnt lgkmcnt(0)" ::: "memory");
      asm volatile("s_waitcnt vmcnt(0)" ::: "memory");
      BARRIER();
      ldsA(1 - c, ANXT);        // A(t+1)
      ldsB(1 - c, 0, Bra);      // Bq0(t+1)
      __builtin_amdgcn_sched_barrier(0);
    }
    MQS(0, 1, ACUR, Brb);       // acc cols 2,3
  };

  stageA(0, 0);
  stageB(0, 0, 0);
  stageB(0, 1, 0);
  asm volatile("s_waitcnt vmcnt(0)" ::: "memory");
  BARRIER();
  ldsA(0, Ara);                 // A(0)
  ldsB(0, 0, Bra);              // Bq0(0)

  for (int tt = 0; tt < nt; tt += 2) {
    tile(tt,     0, Ara, Arb);
    tile(tt + 1, 1, Arb, Ara);
  }

  const int r0 = (lane >> 4) * 4;
#pragma unroll
  for (int m = 0; m < 4; ++m) {
    const int grow = rowBase + wr * 64 + m * 16 + r0;
#pragma unroll
    for (int jj = 0; jj < 4; ++jj) {
      const size_t rOff = (size_t)(grow + jj) * (size_t)ldc;
      if constexpr (BF16OUT) {
        u16* C = (u16*)Cv + z * sCz;
#pragma unroll
        for (int n = 0; n < 4; ++n) {
          const int gcol = colBase + (n >> 1) * 128 + (n & 1) * 64 + wc * 16 + fr;
          C[rOff + gcol] = f2bf(acc[m][n][jj] * alpha);
        }
      } else {
        float* C = (float*)Cv + z * sCz;
#pragma unroll
        for (int n = 0; n < 4; ++n) {
          const int gcol = colBase + (n >> 1) * 128 + (n & 1) * 64 + wc * 16 + fr;
          C[rOff + gcol] = acc[m][n][jj] * alpha;
        }
      }
    }
  }
}

// ---------------------------------------------------------------------------
// Row softmax over 2048 cols: reads bf16 scores (already scaled by 1/32),
// writes fp32 weights (required output) + bf16 probs IN PLACE over scores.
// ---------------------------------------------------------------------------
__global__ __launch_bounds__(256)
void softmax_rows(u16* __restrict__ sbf, float* __restrict__ wfp) {
  const size_t row = blockIdx.x;
  const int tid = threadIdx.x;
  u16* pb = sbf + row * 2048;
  u16x8 xb = *(const u16x8*)(pb + tid * 8);
  float x[8];
#pragma unroll
  for (int j = 0; j < 8; ++j) x[j] = bf2f(xb[j]);
  float m = x[0];
#pragma unroll
  for (int j = 1; j < 8; ++j) m = fmaxf(m, x[j]);
#pragma unroll
  for (int o = 32; o; o >>= 1) m = fmaxf(m, __shfl_xor(m, o, 64));
  __shared__ float red[8];
  if ((tid & 63) == 0) red[tid >> 6] = m;
  __syncthreads();
  m = fmaxf(fmaxf(red[0], red[1]), fmaxf(red[2], red[3]));
  float e[8];
  float s = 0.f;
#pragma unroll
  for (int j = 0; j < 8; ++j) { e[j] = expf(x[j] - m); s += e[j]; }
#pragma unroll
  for (int o = 32; o; o >>= 1) s += __shfl_xor(s, o, 64);
  if ((tid & 63) == 0) red[4 + (tid >> 6)] = s;
  __syncthreads();
  s = (red[4] + red[5]) + (red[6] + red[7]);
  const float inv = 1.0f / s;
  float w[8];
#pragma unroll
  for (int j = 0; j < 8; ++j) w[j] = e[j] * inv;
  float* pf = wfp + row * 2048;
  float4 o0 = {w[0], w[1], w[2], w[3]};
  float4 o1 = {w[4], w[5], w[6], w[7]};
  ((float4*)pf)[tid * 2] = o0;
  ((float4*)pf)[tid * 2 + 1] = o1;
  u16x8 ub;
#pragma unroll
  for (int j = 0; j < 8; ++j) ub[j] = f2bf(w[j]);
  *(u16x8*)(pb + tid * 8) = ub;
}

// ---------------------------------------------------------------------------
// S=2048, B=4, E=1024. inputs: Q, K(ignored), V(ignored), W_in, W_out (fp32)
// outputs: out [2048,4,1024] fp32 | weights [4,2048,2048] fp32
// Graph: cvt -> qkv(p1 q,k | p2 v) -> {scores -> softmax | VWT} -> out'
// with out = P * (V * Wo^T)   [associativity; same FLOPs, no transpose_v]
// ---------------------------------------------------------------------------
extern "C" void kernel_launch(void* const* d_in, const int* in_sizes, int n_in,
                              void* d_out, int out_size, void* d_ws, size_t ws_size,
                              hipStream_t stream) {
  const float* Q  = (const float*)d_in[0];
  const float* Wi = (const float*)d_in[3];
  const float* Wo = (const float*)d_in[4];
  float* out0    = (float*)d_out;
  float* weights = out0 + (size_t)2048 * 4 * 1024;  // 8388608

  char* ws = (char*)d_ws;
  u16* Qb   = (u16*)(ws);                          // 16 MiB [8192][1024]
  u16* Wib  = (u16*)(ws + ((size_t)16 << 20));     //  6 MiB [3072][1024]
  u16* Wob  = (u16*)(ws + ((size_t)22 << 20));     //  2 MiB [1024][1024]
  u16* qkvb = (u16*)(ws + ((size_t)24 << 20));     // 48 MiB [8192][3072]
  u16* vwT  = (u16*)(ws + ((size_t)72 << 20));     // 16 MiB [4][1024f][2048s]
  u16* wbf  = (u16*)(ws + ((size_t)88 << 20));     // 32 MiB [4][2048][2048]

  // 1) converts
  cvt_bf16<<<dim3(8192), dim3(256), 0, stream>>>(Q,  Qb,  2097152);
  cvt_bf16<<<dim3(3072), dim3(256), 0, stream>>>(Wi, Wib, 786432);
  cvt_bf16<<<dim3(1024), dim3(256), 0, stream>>>(Wo, Wob, 262144);

  // 2a) qkv cols 0..2047 (q,k): 8x32 = 256 blocks, exactly 1 round
  gemm256<true><<<dim3(8, 32, 1), dim3(512), 0, stream>>>(
      Qb, Wib, (void*)qkvb, 1024, 1024, 3072, 0, 0, 0, 1024, 1.0f);

  // 2b) qkv cols 2048..3071 (v): 128-row tiles, 4x64 = 256 blocks
  gemm128<true><<<dim3(4, 64, 1), dim3(512), 0, stream>>>(
      Qb, Wib + (size_t)2048 * 1024, (void*)(qkvb + 2048),
      1024, 1024, 3072, 0, 0, 0, 1024, 1.0f);

  // 3) scores[b] = (q/32) k^T -> bf16 into wbf (8x8x4 = 256 blocks)
  gemm256<true><<<dim3(8, 8, 4), dim3(512), 0, stream>>>(
      qkvb, qkvb + 1024, (void*)wbf, 12288, 12288, 2048,
      3072LL, 3072LL, 4194304LL, 1024, 0.03125f);

  // 4) VWT[b][f][s] = sum_e Wo[f,e] v[b,s,e]  (A=Wob shared, B=v rows)
  //    8x8x4 = 256 blocks, nt=16
  gemm128<true><<<dim3(8, 8, 4), dim3(512), 0, stream>>>(
      Wob, qkvb + 2048, (void*)vwT, 1024, 12288, 2048,
      0LL, 3072LL, 2097152LL, 1024, 1.0f);

  // 5) softmax: bf16 scores -> fp32 weights (d_out) + bf16 probs in place
  softmax_rows<<<dim3(8192), dim3(256), 0, stream>>>(wbf, weights);

  // 6) out[t,b,f] = sum_s P[b,t,s] VWT[b,f,s] -> fp32 d_out directly
  //    4x16x4 = 256 blocks, nt=32
  gemm128<false><<<dim3(4, 16, 4), dim3(512), 0, stream>>>(
      wbf, vwT, (void*)out0, 2048, 2048, 4096,
      4194304LL, 2097152LL, 1024LL, 2048, 1.0f);
}